// Round 5
// baseline (43.711 us; speedup 1.0000x reference)
//
#include <hip/hip_runtime.h>
#include <math.h>

#define H      4096
#define NH     32
#define NKV    8
#define HD     128
#define CACHE  2048
#define GROUPS (NH / NKV)
#define CHUNK  32                      // positions per attention block
#define NSPL   (CACHE / CHUNK)         // max splits = 64
#define KSTR   132                     // LDS row stride (floats)
#define SCALE  0.08838834764831845f    // 1/sqrt(128)

typedef float v4f __attribute__((ext_vector_type(4)));

// workspace layout (floats)
#define QOFF 0                         // q_raw[4096]
#define KOFF 4096                      // k_raw[1024]
#define VOFF 5120                      // v_raw[1024]
#define POFF 6144                      // partials: [NH][NSPL]{m,l,pad,pad,acc[128]}
#define PSTRIDE 132
#define CTXOFF (POFF + NH * NSPL * PSTRIDE)   // ctx[4096]

// ---- QKV GEMV: wave per row, dual half-row streams, nontemporal weight loads ----
__global__ __launch_bounds__(256, 4) void qkv_gemv(
    const float* __restrict__ x,
    const float* __restrict__ qw, const float* __restrict__ kw,
    const float* __restrict__ vw, float* __restrict__ ws) {
  __shared__ float xs[H];              // 16 KB
  const int t = threadIdx.x;
  {
    const float4* xr = (const float4*)x;
    float4* xsv = (float4*)xs;
#pragma unroll
    for (int i = 0; i < 4; ++i) xsv[i * 256 + t] = xr[i * 256 + t];
  }
  __syncthreads();

  const int wave = t >> 6;
  const int lane = t & 63;
  const int row  = blockIdx.x * 4 + wave;        // 0..6143

  const float* w;
  float* outp;
  int r;
  if (row < 4096)      { w = qw; r = row;        outp = ws + QOFF; }
  else if (row < 5120) { w = kw; r = row - 4096; outp = ws + KOFF; }
  else                 { w = vw; r = row - 5120; outp = ws + VOFF; }

  const v4f* w0 = (const v4f*)(w + (size_t)r * H);         // cols 0..2047
  const v4f* w1 = w0 + 512;                                // cols 2048..4095

  float s0 = 0.f, s1 = 0.f;
#pragma unroll
  for (int j = 0; j < 8; ++j) {
    const v4f a0 = __builtin_nontemporal_load(&w0[j * 64 + lane]);
    const v4f a1 = __builtin_nontemporal_load(&w1[j * 64 + lane]);
    const float4 b0 = *(const float4*)&xs[(j * 64 + lane) * 4];
    const float4 b1 = *(const float4*)&xs[2048 + (j * 64 + lane) * 4];
    s0 = fmaf(a0.x, b0.x, s0); s0 = fmaf(a0.y, b0.y, s0);
    s0 = fmaf(a0.z, b0.z, s0); s0 = fmaf(a0.w, b0.w, s0);
    s1 = fmaf(a1.x, b1.x, s1); s1 = fmaf(a1.y, b1.y, s1);
    s1 = fmaf(a1.z, b1.z, s1); s1 = fmaf(a1.w, b1.w, s1);
  }
  float sum = s0 + s1;
#pragma unroll
  for (int off = 32; off > 0; off >>= 1) sum += __shfl_xor(sum, off);
  if (lane == 0) outp[r] = sum;
}

// ------------- attention: block = (kv head, 32-pos chunk), all 4 q-heads -------------
__global__ __launch_bounds__(256) void attn_split(
    const float* __restrict__ kcache, const float* __restrict__ vcache,
    const float* __restrict__ cosc, const float* __restrict__ sinc,
    const int* __restrict__ curp, float* __restrict__ ws) {
  const int kh    = blockIdx.x;
  const int split = blockIdx.y;
  const int cur   = curp[0];
  const int total = cur + 1;
  const int p0    = split * CHUNK;
  if (p0 >= total) return;

  __shared__ float Ks[CHUNK * KSTR];
  __shared__ float Vs[CHUNK * KSTR];
  __shared__ float q_s[GROUPS * HD];
  __shared__ float es[GROUPS][CHUNK];

  const int t = threadIdx.x;

  // ---- stage K/V chunk into LDS: batched float4 loads, 8 rows/round
  {
    const int r4 = t >> 5;            // 0..7
    const int c4 = (t & 31) * 4;      // float offset within row
    const float* kb = kcache + (size_t)kh * CACHE * HD;
    const float* vb = vcache + (size_t)kh * CACHE * HD;
#pragma unroll
    for (int rr = 0; rr < CHUNK; rr += 8) {
      const int row = rr + r4;
      const int p   = min(p0 + row, cur);      // clamp: rows past cur masked later
      if (p0 + row != cur) {                   // row 'cur' filled from fresh k/v below
        float4 kv = *(const float4*)(kb + (size_t)p * HD + c4);
        float4 vv = *(const float4*)(vb + (size_t)p * HD + c4);
        *(float4*)&Ks[row * KSTR + c4] = kv;
        *(float4*)&Vs[row * KSTR + c4] = vv;
      }
    }
  }
  // ---- RoPE q for this group's 4 heads (512 values, 2/thread)
#pragma unroll
  for (int i = 0; i < 2; ++i) {
    const int idx = t + i * 256;
    const int qh = idx >> 7, d = idx & 127;
    const int h = kh * GROUPS + qh;
    const float c  = cosc[(size_t)cur * HD + d];
    const float s  = sinc[(size_t)cur * HD + d];
    const float x1 = ws[QOFF + h * HD + d];
    const float x2 = (d < HD / 2) ? -ws[QOFF + h * HD + d + HD / 2]
                                  :  ws[QOFF + h * HD + d - HD / 2];
    q_s[qh * HD + d] = x1 * c + x2 * s;
  }
  // ---- fresh k (RoPE'd) / v into row cur-p0 if this chunk contains cur
  if (cur >= p0 && cur < p0 + CHUNK) {
    const int row = cur - p0;
    if (t < HD) {
      const int d = t;
      const float c  = cosc[(size_t)cur * HD + d];
      const float s  = sinc[(size_t)cur * HD + d];
      const float k1 = ws[KOFF + kh * HD + d];
      const float k2 = (d < HD / 2) ? -ws[KOFF + kh * HD + d + HD / 2]
                                    :  ws[KOFF + kh * HD + d - HD / 2];
      Ks[row * KSTR + d] = k1 * c + k2 * s;
    } else if (t < 2 * HD) {
      const int d = t - HD;
      Vs[row * KSTR + d] = ws[VOFF + kh * HD + d];
    }
  }
  __syncthreads();

  // ---- scores + softmax: thread t<128 owns one (qh, pos); 32-lane group = one qh
  if (t < 128) {
    const int qh = t >> 5, pos = t & 31;
    float4 a = make_float4(0.f, 0.f, 0.f, 0.f);
#pragma unroll
    for (int j = 0; j < HD / 4; ++j) {
      float4 kv = *(const float4*)&Ks[pos * KSTR + j * 4];
      float4 qv = *(const float4*)&q_s[qh * HD + j * 4];
      a.x += kv.x * qv.x; a.y += kv.y * qv.y;
      a.z += kv.z * qv.z; a.w += kv.w * qv.w;
    }
    float s = (a.x + a.y + a.z + a.w) * SCALE;
    const bool valid = (p0 + pos) < total;
    s = valid ? s : -INFINITY;
    float m = s;
#pragma unroll
    for (int off = 16; off > 0; off >>= 1) m = fmaxf(m, __shfl_xor(m, off));
    const float e = valid ? __expf(s - m) : 0.f;
    float l = e;
#pragma unroll
    for (int off = 16; off > 0; off >>= 1) l += __shfl_xor(l, off);
    es[qh][pos] = e;
    if (pos == 0) {
      float* part = ws + POFF + (size_t)((kh * GROUPS + qh) * NSPL + split) * PSTRIDE;
      part[0] = m; part[1] = l;
    }
  }
  __syncthreads();

  // ---- P.V from LDS: thread -> (qh, d-pair), unrolled 32-pos loop
  {
    const int qh = t >> 6;
    const int d0 = (t & 63) * 2;
    float2 acc = make_float2(0.f, 0.f);
#pragma unroll
    for (int pos = 0; pos < CHUNK; ++pos) {
      const float w = es[qh][pos];
      const float2 vv = *(const float2*)&Vs[pos * KSTR + d0];
      acc.x += w * vv.x; acc.y += w * vv.y;
    }
    float* part = ws + POFF + (size_t)((kh * GROUPS + qh) * NSPL + split) * PSTRIDE;
    part[4 + d0]     = acc.x;
    part[4 + d0 + 1] = acc.y;
  }
}

// ---------------- combine splits ----------------
__global__ __launch_bounds__(128) void attn_combine(
    const int* __restrict__ curp, float* __restrict__ ws) {
  const int h = blockIdx.x;
  const int t = threadIdx.x;
  const int total = curp[0] + 1;
  const int nspl = (total + CHUNK - 1) / CHUNK;
  __shared__ float wsh[64];
  __shared__ float Lsh;

  if (t < 64) {
    float mt = -INFINITY, lt = 0.f;
    if (t < nspl) {
      const float* part = ws + POFF + (size_t)(h * NSPL + t) * PSTRIDE;
      mt = part[0]; lt = part[1];
    }
    float M = mt;
#pragma unroll
    for (int off = 32; off > 0; off >>= 1) M = fmaxf(M, __shfl_xor(M, off));
    const float w = (t < nspl) ? __expf(mt - M) : 0.f;
    float lw = lt * w;
#pragma unroll
    for (int off = 32; off > 0; off >>= 1) lw += __shfl_xor(lw, off);
    wsh[t] = w;
    if (t == 0) Lsh = lw;
  }
  __syncthreads();

  const float Linv = 1.f / Lsh;
  float acc = 0.f;
#pragma unroll 8
  for (int i = 0; i < nspl; ++i)
    acc += wsh[i] * ws[POFF + (size_t)(h * NSPL + i) * PSTRIDE + 4 + t];
  ws[CTXOFF + h * HD + t] = acc * Linv;
}

// ---- output GEMV: wave per row, dual streams, nontemporal weight loads ----
__global__ __launch_bounds__(256, 4) void o_gemv(
    const float* __restrict__ ow, const float* __restrict__ ws,
    float* __restrict__ out) {
  __shared__ float xs[H];              // 16 KB (ctx)
  const int t = threadIdx.x;
  {
    const float4* xr = (const float4*)(ws + CTXOFF);
    float4* xsv = (float4*)xs;
#pragma unroll
    for (int i = 0; i < 4; ++i) xsv[i * 256 + t] = xr[i * 256 + t];
  }
  __syncthreads();

  const int wave = t >> 6;
  const int lane = t & 63;
  const int row  = blockIdx.x * 4 + wave;

  const v4f* w0 = (const v4f*)(ow + (size_t)row * H);
  const v4f* w1 = w0 + 512;

  float s0 = 0.f, s1 = 0.f;
#pragma unroll
  for (int j = 0; j < 8; ++j) {
    const v4f a0 = __builtin_nontemporal_load(&w0[j * 64 + lane]);
    const v4f a1 = __builtin_nontemporal_load(&w1[j * 64 + lane]);
    const float4 b0 = *(const float4*)&xs[(j * 64 + lane) * 4];
    const float4 b1 = *(const float4*)&xs[2048 + (j * 64 + lane) * 4];
    s0 = fmaf(a0.x, b0.x, s0); s0 = fmaf(a0.y, b0.y, s0);
    s0 = fmaf(a0.z, b0.z, s0); s0 = fmaf(a0.w, b0.w, s0);
    s1 = fmaf(a1.x, b1.x, s1); s1 = fmaf(a1.y, b1.y, s1);
    s1 = fmaf(a1.z, b1.z, s1); s1 = fmaf(a1.w, b1.w, s1);
  }
  float sum = s0 + s1;
#pragma unroll
  for (int off = 32; off > 0; off >>= 1) sum += __shfl_xor(sum, off);
  if (lane == 0) out[row] = sum;
}

extern "C" void kernel_launch(void* const* d_in, const int* in_sizes, int n_in,
                              void* d_out, int out_size, void* d_ws, size_t ws_size,
                              hipStream_t stream) {
  const float* hs   = (const float*)d_in[0];   // hidden_states (1,1,4096)
  const float* kc   = (const float*)d_in[2];   // (1,8,2048,128)
  const float* vc   = (const float*)d_in[3];
  const float* qw   = (const float*)d_in[4];   // (4096,4096)
  const float* kw   = (const float*)d_in[5];   // (1024,4096)
  const float* vw   = (const float*)d_in[6];   // (1024,4096)
  const float* ow   = (const float*)d_in[7];   // (4096,4096)
  const float* cosc = (const float*)d_in[8];   // (1,4096,128)
  const float* sinc = (const float*)d_in[9];
  const int*   cur  = (const int*)d_in[11];    // current_pos scalar
  float* ws  = (float*)d_ws;
  float* out = (float*)d_out;

  qkv_gemv<<<1536, 256, 0, stream>>>(hs, qw, kw, vw, ws);
  attn_split<<<dim3(NKV, NSPL), 256, 0, stream>>>(kc, vc, cosc, sinc, cur, ws);
  attn_combine<<<NH, 128, 0, stream>>>(cur, ws);
  o_gemv<<<1024, 256, 0, stream>>>(ow, ws, out);
}

// Round 6
// 42.145 us; speedup vs baseline: 1.0372x; 1.0372x over previous
//
#include <hip/hip_runtime.h>
#include <math.h>

#define H      4096
#define NH     32
#define NKV    8
#define HD     128
#define CACHE  2048
#define GROUPS (NH / NKV)
#define CHUNK  32                      // positions per attention block
#define NSPL   (CACHE / CHUNK)         // max splits = 64
#define KSTR   132                     // LDS row stride (floats)
#define SCALE  0.08838834764831845f    // 1/sqrt(128)

typedef float v4f __attribute__((ext_vector_type(4)));

// workspace layout (floats)
#define QOFF 0                         // q_raw[4096]
#define KOFF 4096                      // k_raw[1024]
#define VOFF 5120                      // v_raw[1024]
#define POFF 6144                      // partials: [NH][NSPL]{m,l,pad,pad,acc[128]}
#define PSTRIDE 132
#define CTXOFF (POFF + NH * NSPL * PSTRIDE)   // ctx[4096]

// ---- QKV GEMV: wave per row; 16 loads forced in flight via sched_barrier ----
__global__ __launch_bounds__(256) void qkv_gemv(
    const float* __restrict__ x,
    const float* __restrict__ qw, const float* __restrict__ kw,
    const float* __restrict__ vw, float* __restrict__ ws) {
  __shared__ float xs[H];              // 16 KB
  const int t = threadIdx.x;
  {
    const float4* xr = (const float4*)x;
    float4* xsv = (float4*)xs;
#pragma unroll
    for (int i = 0; i < 4; ++i) xsv[i * 256 + t] = xr[i * 256 + t];
  }
  __syncthreads();

  const int wave = t >> 6;
  const int lane = t & 63;
  const int row  = blockIdx.x * 4 + wave;        // 0..6143

  const float* w;
  float* outp;
  int r;
  if (row < 4096)      { w = qw; r = row;        outp = ws + QOFF; }
  else if (row < 5120) { w = kw; r = row - 4096; outp = ws + KOFF; }
  else                 { w = vw; r = row - 5120; outp = ws + VOFF; }

  const v4f* wr = (const v4f*)(w + (size_t)r * H);

  v4f a0, a1, a2, a3, a4, a5, a6, a7, a8, a9, a10, a11, a12, a13, a14, a15;
  a0  = wr[ 0 * 64 + lane];  a1  = wr[ 1 * 64 + lane];
  a2  = wr[ 2 * 64 + lane];  a3  = wr[ 3 * 64 + lane];
  a4  = wr[ 4 * 64 + lane];  a5  = wr[ 5 * 64 + lane];
  a6  = wr[ 6 * 64 + lane];  a7  = wr[ 7 * 64 + lane];
  a8  = wr[ 8 * 64 + lane];  a9  = wr[ 9 * 64 + lane];
  a10 = wr[10 * 64 + lane];  a11 = wr[11 * 64 + lane];
  a12 = wr[12 * 64 + lane];  a13 = wr[13 * 64 + lane];
  a14 = wr[14 * 64 + lane];  a15 = wr[15 * 64 + lane];
  __builtin_amdgcn_sched_barrier(0);   // all 16 loads issued before any FMA

  float sum = 0.f;
#define FMA4(A, J) {                                            \
    const float4 b = *(const float4*)&xs[((J) * 64 + lane) * 4];\
    sum = fmaf(A.x, b.x, sum); sum = fmaf(A.y, b.y, sum);       \
    sum = fmaf(A.z, b.z, sum); sum = fmaf(A.w, b.w, sum); }
  FMA4(a0, 0)   FMA4(a1, 1)   FMA4(a2, 2)   FMA4(a3, 3)
  FMA4(a4, 4)   FMA4(a5, 5)   FMA4(a6, 6)   FMA4(a7, 7)
  FMA4(a8, 8)   FMA4(a9, 9)   FMA4(a10, 10) FMA4(a11, 11)
  FMA4(a12, 12) FMA4(a13, 13) FMA4(a14, 14) FMA4(a15, 15)
#undef FMA4

#pragma unroll
  for (int off = 32; off > 0; off >>= 1) sum += __shfl_xor(sum, off);
  if (lane == 0) outp[r] = sum;
}

// ------------- attention: block = (kv head, 32-pos chunk), all 4 q-heads -------------
__global__ __launch_bounds__(256) void attn_split(
    const float* __restrict__ kcache, const float* __restrict__ vcache,
    const float* __restrict__ cosc, const float* __restrict__ sinc,
    const int* __restrict__ curp, float* __restrict__ ws) {
  const int kh    = blockIdx.x;
  const int split = blockIdx.y;
  const int cur   = curp[0];
  const int total = cur + 1;
  const int p0    = split * CHUNK;
  if (p0 >= total) return;

  __shared__ float Ks[CHUNK * KSTR];
  __shared__ float Vs[CHUNK * KSTR];
  __shared__ float q_s[GROUPS * HD];
  __shared__ float es[GROUPS][CHUNK];

  const int t = threadIdx.x;

  // ---- stage K/V chunk into LDS: batched float4 loads, 8 rows/round
  {
    const int r4 = t >> 5;            // 0..7
    const int c4 = (t & 31) * 4;      // float offset within row
    const float* kb = kcache + (size_t)kh * CACHE * HD;
    const float* vb = vcache + (size_t)kh * CACHE * HD;
#pragma unroll
    for (int rr = 0; rr < CHUNK; rr += 8) {
      const int row = rr + r4;
      const int p   = min(p0 + row, cur);      // clamp: rows past cur masked later
      if (p0 + row != cur) {                   // row 'cur' filled from fresh k/v below
        float4 kv = *(const float4*)(kb + (size_t)p * HD + c4);
        float4 vv = *(const float4*)(vb + (size_t)p * HD + c4);
        *(float4*)&Ks[row * KSTR + c4] = kv;
        *(float4*)&Vs[row * KSTR + c4] = vv;
      }
    }
  }
  // ---- RoPE q for this group's 4 heads (512 values, 2/thread)
#pragma unroll
  for (int i = 0; i < 2; ++i) {
    const int idx = t + i * 256;
    const int qh = idx >> 7, d = idx & 127;
    const int h = kh * GROUPS + qh;
    const float c  = cosc[(size_t)cur * HD + d];
    const float s  = sinc[(size_t)cur * HD + d];
    const float x1 = ws[QOFF + h * HD + d];
    const float x2 = (d < HD / 2) ? -ws[QOFF + h * HD + d + HD / 2]
                                  :  ws[QOFF + h * HD + d - HD / 2];
    q_s[qh * HD + d] = x1 * c + x2 * s;
  }
  // ---- fresh k (RoPE'd) / v into row cur-p0 if this chunk contains cur
  if (cur >= p0 && cur < p0 + CHUNK) {
    const int row = cur - p0;
    if (t < HD) {
      const int d = t;
      const float c  = cosc[(size_t)cur * HD + d];
      const float s  = sinc[(size_t)cur * HD + d];
      const float k1 = ws[KOFF + kh * HD + d];
      const float k2 = (d < HD / 2) ? -ws[KOFF + kh * HD + d + HD / 2]
                                    :  ws[KOFF + kh * HD + d - HD / 2];
      Ks[row * KSTR + d] = k1 * c + k2 * s;
    } else if (t < 2 * HD) {
      const int d = t - HD;
      Vs[row * KSTR + d] = ws[VOFF + kh * HD + d];
    }
  }
  __syncthreads();

  // ---- scores + softmax: thread t<128 owns one (qh, pos); 32-lane group = one qh
  if (t < 128) {
    const int qh = t >> 5, pos = t & 31;
    float4 a = make_float4(0.f, 0.f, 0.f, 0.f);
#pragma unroll
    for (int j = 0; j < HD / 4; ++j) {
      float4 kv = *(const float4*)&Ks[pos * KSTR + j * 4];
      float4 qv = *(const float4*)&q_s[qh * HD + j * 4];
      a.x += kv.x * qv.x; a.y += kv.y * qv.y;
      a.z += kv.z * qv.z; a.w += kv.w * qv.w;
    }
    float s = (a.x + a.y + a.z + a.w) * SCALE;
    const bool valid = (p0 + pos) < total;
    s = valid ? s : -INFINITY;
    float m = s;
#pragma unroll
    for (int off = 16; off > 0; off >>= 1) m = fmaxf(m, __shfl_xor(m, off));
    const float e = valid ? __expf(s - m) : 0.f;
    float l = e;
#pragma unroll
    for (int off = 16; off > 0; off >>= 1) l += __shfl_xor(l, off);
    es[qh][pos] = e;
    if (pos == 0) {
      float* part = ws + POFF + (size_t)((kh * GROUPS + qh) * NSPL + split) * PSTRIDE;
      part[0] = m; part[1] = l;
    }
  }
  __syncthreads();

  // ---- P.V from LDS: thread -> (qh, d-pair), unrolled 32-pos loop
  {
    const int qh = t >> 6;
    const int d0 = (t & 63) * 2;
    float2 acc = make_float2(0.f, 0.f);
#pragma unroll
    for (int pos = 0; pos < CHUNK; ++pos) {
      const float w = es[qh][pos];
      const float2 vv = *(const float2*)&Vs[pos * KSTR + d0];
      acc.x += w * vv.x; acc.y += w * vv.y;
    }
    float* part = ws + POFF + (size_t)((kh * GROUPS + qh) * NSPL + split) * PSTRIDE;
    part[4 + d0]     = acc.x;
    part[4 + d0 + 1] = acc.y;
  }
}

// ---------------- combine splits ----------------
__global__ __launch_bounds__(128) void attn_combine(
    const int* __restrict__ curp, float* __restrict__ ws) {
  const int h = blockIdx.x;
  const int t = threadIdx.x;
  const int total = curp[0] + 1;
  const int nspl = (total + CHUNK - 1) / CHUNK;
  __shared__ float wsh[64];
  __shared__ float Lsh;

  if (t < 64) {
    float mt = -INFINITY, lt = 0.f;
    if (t < nspl) {
      const float* part = ws + POFF + (size_t)(h * NSPL + t) * PSTRIDE;
      mt = part[0]; lt = part[1];
    }
    float M = mt;
#pragma unroll
    for (int off = 32; off > 0; off >>= 1) M = fmaxf(M, __shfl_xor(M, off));
    const float w = (t < nspl) ? __expf(mt - M) : 0.f;
    float lw = lt * w;
#pragma unroll
    for (int off = 32; off > 0; off >>= 1) lw += __shfl_xor(lw, off);
    wsh[t] = w;
    if (t == 0) Lsh = lw;
  }
  __syncthreads();

  const float Linv = 1.f / Lsh;
  float acc = 0.f;
#pragma unroll 8
  for (int i = 0; i < nspl; ++i)
    acc += wsh[i] * ws[POFF + (size_t)(h * NSPL + i) * PSTRIDE + 4 + t];
  ws[CTXOFF + h * HD + t] = acc * Linv;
}

// ---- output GEMV: same forced 16-deep burst ----
__global__ __launch_bounds__(256) void o_gemv(
    const float* __restrict__ ow, const float* __restrict__ ws,
    float* __restrict__ out) {
  __shared__ float xs[H];              // 16 KB (ctx)
  const int t = threadIdx.x;
  {
    const float4* xr = (const float4*)(ws + CTXOFF);
    float4* xsv = (float4*)xs;
#pragma unroll
    for (int i = 0; i < 4; ++i) xsv[i * 256 + t] = xr[i * 256 + t];
  }
  __syncthreads();

  const int wave = t >> 6;
  const int lane = t & 63;
  const int row  = blockIdx.x * 4 + wave;

  const v4f* wr = (const v4f*)(ow + (size_t)row * H);

  v4f a0, a1, a2, a3, a4, a5, a6, a7, a8, a9, a10, a11, a12, a13, a14, a15;
  a0  = wr[ 0 * 64 + lane];  a1  = wr[ 1 * 64 + lane];
  a2  = wr[ 2 * 64 + lane];  a3  = wr[ 3 * 64 + lane];
  a4  = wr[ 4 * 64 + lane];  a5  = wr[ 5 * 64 + lane];
  a6  = wr[ 6 * 64 + lane];  a7  = wr[ 7 * 64 + lane];
  a8  = wr[ 8 * 64 + lane];  a9  = wr[ 9 * 64 + lane];
  a10 = wr[10 * 64 + lane];  a11 = wr[11 * 64 + lane];
  a12 = wr[12 * 64 + lane];  a13 = wr[13 * 64 + lane];
  a14 = wr[14 * 64 + lane];  a15 = wr[15 * 64 + lane];
  __builtin_amdgcn_sched_barrier(0);

  float sum = 0.f;
#define FMA4(A, J) {                                            \
    const float4 b = *(const float4*)&xs[((J) * 64 + lane) * 4];\
    sum = fmaf(A.x, b.x, sum); sum = fmaf(A.y, b.y, sum);       \
    sum = fmaf(A.z, b.z, sum); sum = fmaf(A.w, b.w, sum); }
  FMA4(a0, 0)   FMA4(a1, 1)   FMA4(a2, 2)   FMA4(a3, 3)
  FMA4(a4, 4)   FMA4(a5, 5)   FMA4(a6, 6)   FMA4(a7, 7)
  FMA4(a8, 8)   FMA4(a9, 9)   FMA4(a10, 10) FMA4(a11, 11)
  FMA4(a12, 12) FMA4(a13, 13) FMA4(a14, 14) FMA4(a15, 15)
#undef FMA4

#pragma unroll
  for (int off = 32; off > 0; off >>= 1) sum += __shfl_xor(sum, off);
  if (lane == 0) out[row] = sum;
}

extern "C" void kernel_launch(void* const* d_in, const int* in_sizes, int n_in,
                              void* d_out, int out_size, void* d_ws, size_t ws_size,
                              hipStream_t stream) {
  const float* hs   = (const float*)d_in[0];   // hidden_states (1,1,4096)
  const float* kc   = (const float*)d_in[2];   // (1,8,2048,128)
  const float* vc   = (const float*)d_in[3];
  const float* qw   = (const float*)d_in[4];   // (4096,4096)
  const float* kw   = (const float*)d_in[5];   // (1024,4096)
  const float* vw   = (const float*)d_in[6];   // (1024,4096)
  const float* ow   = (const float*)d_in[7];   // (4096,4096)
  const float* cosc = (const float*)d_in[8];   // (1,4096,128)
  const float* sinc = (const float*)d_in[9];
  const int*   cur  = (const int*)d_in[11];    // current_pos scalar
  float* ws  = (float*)d_ws;
  float* out = (float*)d_out;

  qkv_gemv<<<1536, 256, 0, stream>>>(hs, qw, kw, vw, ws);
  attn_split<<<dim3(NKV, NSPL), 256, 0, stream>>>(kc, vc, cosc, sinc, cur, ws);
  attn_combine<<<NH, 128, 0, stream>>>(cur, ws);
  o_gemv<<<1024, 256, 0, stream>>>(ow, ws, out);
}